// Round 14
// baseline (161.896 us; speedup 1.0000x reference)
//
#include <hip/hip_runtime.h>
#include <hip/hip_bf16.h>
#include <math.h>

#define T_TOKENS 4096
#define HID 512
#define INTER 2048
#define NEXP 8

typedef __bf16 bf16x8 __attribute__((ext_vector_type(8)));
typedef __bf16 bf16x4 __attribute__((ext_vector_type(4)));
typedef float f32x4 __attribute__((ext_vector_type(4)));

#define GLD16(g, l) __builtin_amdgcn_global_load_lds( \
    (const __attribute__((address_space(1))) void*)(g), \
    (__attribute__((address_space(3))) void*)(l), 16, 0, 0)

// ---------------- fused prologue: router (blocks 0..1023) + wu-transpose (1024..3071)
// ---------------- + wd-transpose (3072..5119). All three are independent.
__device__ __forceinline__ void transpose_tile(const float* __restrict__ in,
                                               __bf16* __restrict__ out,
                                               int R, int C, int r0, int c0,
                                               __bf16 (*tile)[68]) {
  int tid = threadIdx.x;
  int rr = tid >> 4;
  int cc = (tid & 15) * 4;
#pragma unroll
  for (int j = 0; j < 4; ++j) {
    int row = j * 16 + rr;
    float4 v = *(const float4*)(in + (size_t)(r0 + row) * C + c0 + cc);
    tile[row][cc + 0] = (__bf16)v.x;
    tile[row][cc + 1] = (__bf16)v.y;
    tile[row][cc + 2] = (__bf16)v.z;
    tile[row][cc + 3] = (__bf16)v.w;
  }
  __syncthreads();
#pragma unroll
  for (int j = 0; j < 4; ++j) {
    int orow = j * 16 + rr;
    bf16x4 o;
    o[0] = tile[cc + 0][orow];
    o[1] = tile[cc + 1][orow];
    o[2] = tile[cc + 2][orow];
    o[3] = tile[cc + 3][orow];
    *(bf16x4*)(out + (size_t)(c0 + orow) * R + r0 + cc) = o;
  }
}

__global__ void prep_kernel(const float* __restrict__ x, const float* __restrict__ wrt,
                            int* __restrict__ topi, float* __restrict__ topw,
                            int* __restrict__ cntpart, float* __restrict__ usagepart,
                            const float* __restrict__ wu, __bf16* __restrict__ wuT,
                            const float* __restrict__ wd, __bf16* __restrict__ wdT) {
  __shared__ float wsm[8 * 512];
  __shared__ float us[8];
  __shared__ int cs[8];
  __shared__ __bf16 tile[64][68];
  int bid = blockIdx.x;
  int tid = threadIdx.x;

  if (bid >= 3072) {               // wd transpose: R=INTER, C=HID
    int b = bid - 3072;
    int e = b >> 8;
    int c0 = (b & 7) * 64;
    int r0 = ((b >> 3) & 31) * 64;
    transpose_tile(wd + (size_t)e * INTER * HID, wdT + (size_t)e * INTER * HID,
                   INTER, HID, r0, c0, tile);
    return;
  }
  if (bid >= 1024) {               // wu transpose: R=HID, C=INTER
    int b = bid - 1024;
    int e = b >> 8;
    int c0 = (b & 31) * 64;
    int r0 = ((b >> 5) & 7) * 64;
    transpose_tile(wu + (size_t)e * HID * INTER, wuT + (size_t)e * HID * INTER,
                   HID, INTER, r0, c0, tile);
    return;
  }

  // router
  if (tid < 8) { us[tid] = 0.f; cs[tid] = 0; }
  for (int i = tid; i < 8 * 512; i += 256) {
    int e = i >> 9, h = i & 511;
    wsm[i] = wrt[h * 8 + e];
  }
  __syncthreads();
  int lane = tid & 63;
  int t = bid * 4 + (tid >> 6);
  const float* xt = x + (size_t)t * HID;
  float a[8];
#pragma unroll
  for (int e = 0; e < 8; ++e) a[e] = 0.f;
#pragma unroll
  for (int j = 0; j < 8; ++j) {
    float xv = xt[lane + j * 64];
#pragma unroll
    for (int e = 0; e < 8; ++e) a[e] += xv * wsm[e * 512 + lane + j * 64];
  }
#pragma unroll
  for (int off = 32; off > 0; off >>= 1) {
#pragma unroll
    for (int e = 0; e < 8; ++e) a[e] += __shfl_xor(a[e], off);
  }
  if (lane == 0) {
    float m = a[0];
#pragma unroll
    for (int e = 1; e < 8; ++e) m = fmaxf(m, a[e]);
    float p[8], s = 0.f;
#pragma unroll
    for (int e = 0; e < 8; ++e) { p[e] = expf(a[e] - m); s += p[e]; }
    float inv = 1.f / s;
#pragma unroll
    for (int e = 0; e < 8; ++e) atomicAdd(&us[e], p[e] * inv);
    int i0 = 0; float v0 = a[0];
#pragma unroll
    for (int e = 1; e < 8; ++e) if (a[e] > v0) { v0 = a[e]; i0 = e; }
    int i1 = -1; float v1 = -3.4e38f;
#pragma unroll
    for (int e = 0; e < 8; ++e) if (e != i0 && a[e] > v1) { v1 = a[e]; i1 = e; }
    float e1 = expf(v1 - v0);
    float w0 = 1.f / (1.f + e1);
    float w1 = e1 * w0;
    topi[t * 2] = i0; topi[t * 2 + 1] = i1;
    topw[t * 2] = w0; topw[t * 2 + 1] = w1;
    atomicAdd(&cs[i0], 1); atomicAdd(&cs[i1], 1);
  }
  __syncthreads();
  if (tid < 8) {
    cntpart[bid * 8 + tid] = cs[tid];
    usagepart[bid * 8 + tid] = us[tid];
  }
}

// ---------------- finalize: reduce partials -> cnt/off + loss/usage tail ----------------
__global__ void finalize_kernel(const int* __restrict__ cntpart, const float* __restrict__ usagepart,
                                int* __restrict__ cnt, int* __restrict__ off,
                                float* __restrict__ tail) {
  __shared__ int ci[256];
  __shared__ float uf[256];
  int tid = threadIdx.x;
  int e = tid >> 5, c = tid & 31;
  int s = 0; float u = 0.f;
  for (int b = c; b < 1024; b += 32) {
    s += cntpart[b * 8 + e];
    u += usagepart[b * 8 + e];
  }
  ci[tid] = s; uf[tid] = u;
  __syncthreads();
  for (int st = 16; st > 0; st >>= 1) {
    if (c < st) { ci[tid] += ci[tid + st]; uf[tid] += uf[tid + st]; }
    __syncthreads();
  }
  if (tid == 0) {
    int o = 0;
    float loss = 0.f;
    for (int e2 = 0; e2 < 8; ++e2) {
      int ce = ci[e2 * 32];
      cnt[e2] = ce;
      off[e2] = o;
      o += (ce + 127) & ~127;
      float uu = uf[e2 * 32] * (1.0f / 4096.0f);
      tail[1 + e2] = uu;
      float d = uu - 0.125f;
      loss += d * d;
    }
    tail[0] = loss;
  }
}

// ---------------- slot assignment: ballot-aggregated, 64 total return-atomics ----------------
__global__ void slotassign_kernel(const int* __restrict__ topi, const float* __restrict__ topw,
                                  const int* __restrict__ off, int* __restrict__ cnt2pad,
                                  int* __restrict__ stok, float* __restrict__ sw,
                                  int* __restrict__ slotof) {
  __shared__ int wavehist[16][8];
  __shared__ int blockbase[8];
  int tid = threadIdx.x, lane = tid & 63, wv = tid >> 6;
  int p = blockIdx.x * 1024 + tid;
  int e = topi[p];
  float w = topw[p];
  unsigned long long mymask = 0;
#pragma unroll
  for (int e2 = 0; e2 < 8; ++e2) {
    unsigned long long m = __ballot(e == e2);
    if (lane == 0) wavehist[wv][e2] = __popcll(m);
    if (e2 == e) mymask = m;
  }
  __syncthreads();
  if (tid < 8) {
    int s = 0;
#pragma unroll
    for (int w2 = 0; w2 < 16; ++w2) s += wavehist[w2][tid];
    blockbase[tid] = atomicAdd(&cnt2pad[tid * 16], s);
  }
  __syncthreads();
  int rank = 0;
  for (int w2 = 0; w2 < wv; ++w2) rank += wavehist[w2][e];
  rank += __popcll(mymask & ((1ull << lane) - 1ull));
  int slot = off[e] + blockbase[e] + rank;
  stok[slot] = p >> 1;
  sw[slot] = w;
  slotof[p] = slot;
}

// ---------------- gather: copy token rows (bf16) into expert-grouped Xg, atomic-free --------
__global__ void gather_kernel(const float* __restrict__ x, const int* __restrict__ slotof,
                              __bf16* __restrict__ Xg) {
  int tid = threadIdx.x, lane = tid & 63;
  int p = blockIdx.x * 4 + (tid >> 6);
  int slot = slotof[p];
  int t = p >> 1;
  const float4* xs = (const float4*)(x + (size_t)t * HID);
  float4 v0 = xs[lane * 2], v1 = xs[lane * 2 + 1];
  bf16x8 o;
  o[0] = (__bf16)v0.x; o[1] = (__bf16)v0.y; o[2] = (__bf16)v0.z; o[3] = (__bf16)v0.w;
  o[4] = (__bf16)v1.x; o[5] = (__bf16)v1.y; o[6] = (__bf16)v1.z; o[7] = (__bf16)v1.w;
  *(bf16x8*)(Xg + (size_t)slot * HID + lane * 8) = o;
}

// ---------------- UP GEMM, B-RESIDENT: 64x64 out tiles, full K=512 B-panel in LDS ----------
// Block = (expert, n-tile, m-half). B n-panel (64 rows x 512 K = 64KB) staged ONCE as 8
// concatenated R8-style [64][128B] chunks (identical swizzle/bank behavior, 0 conflicts);
// then the m-loop streams only A (8KB per K-step) through the proven {stage, sync, 32 MFMA,
// sync} structure. B staging traffic: 256 -> 16 MB. LDS 72KB -> 2 blocks/CU.
__launch_bounds__(256, 2)
__global__ void gemm_up_bres(const __bf16* __restrict__ A, const __bf16* __restrict__ Ball,
                             __bf16* __restrict__ Hout,
                             const int* __restrict__ offp, const int* __restrict__ cntp) {
  int bid = blockIdx.x;
  int e = bid & 7;               // expert -> XCD pin
  int r = bid >> 3;
  int nt = r & 31;               // 32 n-tiles (N=2048)
  int mh = r >> 5;               // m-half: 12 m-tile capacity each
  int n0 = nt * 64;
  int cnte = cntp[e];
  int mts = mh * 12;
  if (mts * 64 >= cnte) return;
  int offe = offp[e];
  const __bf16* B = Ball + (size_t)e * INTER * HID;

  __shared__ char smem[73728];   // Bres 64KB (8 chunks x [64][128B]) + As 8KB
  char* Bres = smem;
  char* As = smem + 65536;

  int tid = threadIdx.x;
  int lane = tid & 63;
  int wid = tid >> 6;
  int wr = wid >> 1, wc = wid & 1;    // 2x2 waves, 32x32 out each

  // ---- stage resident B panel: 8 chunks, each chunk c holds K range [c*64, c*64+64) ----
#pragma unroll
  for (int c = 0; c < 8; ++c) {
#pragma unroll
    for (int q = 0; q < 2; ++q) {
      int L = q * 4096 + tid * 16;
      int row = L >> 7;
      int kb = L & 127;
      int kbs = kb ^ ((row & 7) << 4);   // inverse-swizzled global source, linear LDS dest
      GLD16((const char*)(B + (size_t)(n0 + row) * HID + c * 64) + kbs,
            Bres + c * 8192 + L);
    }
  }
  __syncthreads();                       // panel resident

  int lim = offe + cnte;
  for (int m = 0; m < 12; ++m) {
    int mt = mts + m;
    if (mt * 64 >= cnte) break;
    int m0 = offe + mt * 64;

    f32x4 acc[2][2];
#pragma unroll
    for (int i = 0; i < 2; ++i)
#pragma unroll
      for (int j = 0; j < 2; ++j) acc[i][j] = (f32x4){0.f, 0.f, 0.f, 0.f};

    for (int it = 0; it < 8; ++it) {
      int k0 = it * 64;
#pragma unroll
      for (int q2 = 0; q2 < 2; ++q2) {
        int L = q2 * 4096 + tid * 16;
        int row = L >> 7;
        int kb = L & 127;
        int kbs = kb ^ ((row & 7) << 4);
        GLD16((const char*)(A + (size_t)(m0 + row) * HID + k0) + kbs, As + L);
      }
      __syncthreads();
      const char* Bc = Bres + it * 8192;
#pragma unroll
      for (int ks = 0; ks < 2; ++ks) {
        bf16x8 av[2], bv[2];
        int kb = ks * 64 + ((lane >> 4) << 4);
#pragma unroll
        for (int i = 0; i < 2; ++i) {
          int rowA = wr * 32 + i * 16 + (lane & 15);
          av[i] = *(const bf16x8*)(As + rowA * 128 + (kb ^ ((rowA & 7) << 4)));
          int rowB = wc * 32 + i * 16 + (lane & 15);
          bv[i] = *(const bf16x8*)(Bc + rowB * 128 + (kb ^ ((rowB & 7) << 4)));
        }
#pragma unroll
        for (int i = 0; i < 2; ++i)
#pragma unroll
          for (int j = 0; j < 2; ++j)
            acc[i][j] = __builtin_amdgcn_mfma_f32_16x16x32_bf16(av[i], bv[j], acc[i][j], 0, 0, 0);
      }
      __syncthreads();                   // protect As before next stage
    }

    // epilogue: gelu -> H (bf16)
#pragma unroll
    for (int i = 0; i < 2; ++i) {
#pragma unroll
      for (int r2 = 0; r2 < 4; ++r2) {
        int slot = m0 + wr * 32 + i * 16 + ((lane >> 4) << 2) + r2;
        if (slot < lim) {
          __bf16* hp = Hout + (size_t)slot * INTER + n0 + wc * 32 + (lane & 15);
#pragma unroll
          for (int j = 0; j < 2; ++j) {
            float v = acc[i][j][r2];
            float g = 0.5f * v * (1.0f + erff(v * 0.70710678118654752f));
            hp[j * 16] = (__bf16)g;
          }
        }
      }
    }
  }
}

// ---------------- DOWN GEMM: exact R13 recipe (64x64, BK=64, full K=2048, XCD-pinned) ------
__launch_bounds__(256, 6)
__global__ void gemm_down(const __bf16* __restrict__ A, const __bf16* __restrict__ Ball,
                          float* __restrict__ Out,
                          const int* __restrict__ stok, const float* __restrict__ sw,
                          const int* __restrict__ offp, const int* __restrict__ cntp) {
  int bid = blockIdx.x;
  int e = bid & 7;               // expert -> XCD pin
  int r = bid >> 3;
  int n0 = (r & 7) * 64;         // 8 n-tiles (N=512), fastest
  int mt = r >> 3;               // 24 m-tile capacity
  int cnte = cntp[e];
  if (mt * 64 >= cnte) return;
  int offe = offp[e];
  int m0 = offe + mt * 64;
  const __bf16* B = Ball + (size_t)e * INTER * HID;

  __shared__ char smem[16384];
  char* As = smem;
  char* Bs = smem + 8192;

  int tid = threadIdx.x;
  int lane = tid & 63;
  int wid = tid >> 6;
  int wr = wid >> 1, wc = wid & 1;

  f32x4 acc[2][2];
#pragma unroll
  for (int i = 0; i < 2; ++i)
#pragma unroll
    for (int j = 0; j < 2; ++j) acc[i][j] = (f32x4){0.f, 0.f, 0.f, 0.f};

  for (int it = 0; it < 32; ++it) {
    int k0 = it * 64;
#pragma unroll
    for (int q2 = 0; q2 < 2; ++q2) {
      int L = q2 * 4096 + tid * 16;
      int row = L >> 7;
      int kb = L & 127;
      int kbs = kb ^ ((row & 7) << 4);
      GLD16((const char*)(A + (size_t)(m0 + row) * INTER + k0) + kbs, As + L);
      GLD16((const char*)(B + (size_t)(n0 + row) * INTER + k0) + kbs, Bs + L);
    }
    __syncthreads();
#pragma unroll
    for (int ks = 0; ks < 2; ++ks) {
      bf16x8 av[2], bv[2];
      int kb = ks * 64 + ((lane >> 4) << 4);
#pragma unroll
      for (int i = 0; i < 2; ++i) {
        int rowA = wr * 32 + i * 16 + (lane & 15);
        av[i] = *(const bf16x8*)(As + rowA * 128 + (kb ^ ((rowA & 7) << 4)));
        int rowB = wc * 32 + i * 16 + (lane & 15);
        bv[i] = *(const bf16x8*)(Bs + rowB * 128 + (kb ^ ((rowB & 7) << 4)));
      }
#pragma unroll
      for (int i = 0; i < 2; ++i)
#pragma unroll
        for (int j = 0; j < 2; ++j)
          acc[i][j] = __builtin_amdgcn_mfma_f32_16x16x32_bf16(av[i], bv[j], acc[i][j], 0, 0, 0);
    }
    __syncthreads();
  }

  int lim = offe + cnte;
#pragma unroll
  for (int i = 0; i < 2; ++i) {
#pragma unroll
    for (int r2 = 0; r2 < 4; ++r2) {
      int slot = m0 + wr * 32 + i * 16 + ((lane >> 4) << 2) + r2;
      if (slot < lim) {
        int t = stok[slot];
        float w = sw[slot];
        float* op = Out + (size_t)t * HID + n0 + wc * 32 + (lane & 15);
#pragma unroll
        for (int j = 0; j < 2; ++j) atomicAdd(op + j * 16, w * acc[i][j][r2]);
      }
    }
  }
}

extern "C" void kernel_launch(void* const* d_in, const int* in_sizes, int n_in,
                              void* d_out, int out_size, void* d_ws, size_t ws_size,
                              hipStream_t stream) {
  const float* x   = (const float*)d_in[0];
  const float* wrt = (const float*)d_in[1];
  const float* wu  = (const float*)d_in[2];
  const float* wd  = (const float*)d_in[3];
  float* out = (float*)d_out;
  char* ws = (char*)d_ws;

  const size_t XG_OFF   = 0;
  const size_t H_OFF    = XG_OFF  + (size_t)9216 * 512 * 2;
  const size_t WUT_OFF  = H_OFF   + (size_t)9216 * 2048 * 2;
  const size_t WDT_OFF  = WUT_OFF + (size_t)8 * 512 * 2048 * 2;
  const size_t TOK_OFF  = WDT_OFF + (size_t)8 * 512 * 2048 * 2;
  const size_t SW_OFF   = TOK_OFF  + (size_t)9216 * 4;
  const size_t TOPI_OFF = SW_OFF   + (size_t)9216 * 4;
  const size_t TOPW_OFF = TOPI_OFF + (size_t)8192 * 4;
  const size_t SLOT_OFF = TOPW_OFF + (size_t)8192 * 4;
  const size_t CPART_OFF = SLOT_OFF + (size_t)8192 * 4;
  const size_t UPART_OFF = CPART_OFF + (size_t)8192 * 4;
  const size_t CTRL_OFF  = UPART_OFF + (size_t)8192 * 4;
  // CTRL: cnt[8] @0, off[8] @64, cnt2pad[8*16] @128  (memset 1KB)

  __bf16* Xg   = (__bf16*)(ws + XG_OFF);
  __bf16* H    = (__bf16*)(ws + H_OFF);
  __bf16* wuT  = (__bf16*)(ws + WUT_OFF);
  __bf16* wdT  = (__bf16*)(ws + WDT_OFF);
  int*    stok = (int*)(ws + TOK_OFF);
  float*  sw   = (float*)(ws + SW_OFF);
  int*    topi = (int*)(ws + TOPI_OFF);
  float*  topw = (float*)(ws + TOPW_OFF);
  int*    slotof = (int*)(ws + SLOT_OFF);
  int*    cntpart = (int*)(ws + CPART_OFF);
  float*  usagepart = (float*)(ws + UPART_OFF);
  int*    cnt  = (int*)(ws + CTRL_OFF);
  int*    off  = (int*)(ws + CTRL_OFF + 64);
  int*    cnt2pad = (int*)(ws + CTRL_OFF + 128);

  hipMemsetAsync(ws + CTRL_OFF, 0, 1024, stream);
  hipMemsetAsync(d_out, 0, (size_t)T_TOKENS * HID * 4, stream);

  // fused: router (1024) + wu transpose (2048) + wd transpose (2048)
  prep_kernel<<<5120, 256, 0, stream>>>(x, wrt, topi, topw, cntpart, usagepart,
                                        wu, wuT, wd, wdT);
  finalize_kernel<<<1, 256, 0, stream>>>(cntpart, usagepart, cnt, off,
                                         out + (size_t)T_TOKENS * HID);
  slotassign_kernel<<<8, 1024, 0, stream>>>(topi, topw, off, cnt2pad, stok, sw, slotof);
  gather_kernel<<<2048, 256, 0, stream>>>(x, slotof, Xg);

  // up: h = gelu(Xg @ wuT^T); B-resident blocks: grid = 8e * (32nt * 2mh) = 512
  gemm_up_bres<<<512, 256, 0, stream>>>(Xg, wuT, H, off, cnt);
  // down: out += w*(h @ wdT^T); grid = 8e * (8nt * 24mt) = 1536, full K (no split)
  gemm_down<<<1536, 256, 0, stream>>>(H, wdT, out, stok, sw, off, cnt);
}

// Round 15
// 123.144 us; speedup vs baseline: 1.3147x; 1.3147x over previous
//
#include <hip/hip_runtime.h>
#include <hip/hip_bf16.h>
#include <math.h>

#define T_TOKENS 4096
#define HID 512
#define INTER 2048
#define NEXP 8

typedef __bf16 bf16x8 __attribute__((ext_vector_type(8)));
typedef __bf16 bf16x4 __attribute__((ext_vector_type(4)));
typedef float f32x4 __attribute__((ext_vector_type(4)));

#define GLD16(g, l) __builtin_amdgcn_global_load_lds( \
    (const __attribute__((address_space(1))) void*)(g), \
    (__attribute__((address_space(3))) void*)(l), 16, 0, 0)

// ---------------- fused prologue: router (blocks 0..1023) + wu-transpose (1024..3071)
// ---------------- + wd-transpose (3072..5119). All three are independent.
__device__ __forceinline__ void transpose_tile(const float* __restrict__ in,
                                               __bf16* __restrict__ out,
                                               int R, int C, int r0, int c0,
                                               __bf16 (*tile)[68]) {
  int tid = threadIdx.x;
  int rr = tid >> 4;
  int cc = (tid & 15) * 4;
#pragma unroll
  for (int j = 0; j < 4; ++j) {
    int row = j * 16 + rr;
    float4 v = *(const float4*)(in + (size_t)(r0 + row) * C + c0 + cc);
    tile[row][cc + 0] = (__bf16)v.x;
    tile[row][cc + 1] = (__bf16)v.y;
    tile[row][cc + 2] = (__bf16)v.z;
    tile[row][cc + 3] = (__bf16)v.w;
  }
  __syncthreads();
#pragma unroll
  for (int j = 0; j < 4; ++j) {
    int orow = j * 16 + rr;
    bf16x4 o;
    o[0] = tile[cc + 0][orow];
    o[1] = tile[cc + 1][orow];
    o[2] = tile[cc + 2][orow];
    o[3] = tile[cc + 3][orow];
    *(bf16x4*)(out + (size_t)(c0 + orow) * R + r0 + cc) = o;
  }
}

__global__ void prep_kernel(const float* __restrict__ x, const float* __restrict__ wrt,
                            int* __restrict__ topi, float* __restrict__ topw,
                            int* __restrict__ cntpart, float* __restrict__ usagepart,
                            const float* __restrict__ wu, __bf16* __restrict__ wuT,
                            const float* __restrict__ wd, __bf16* __restrict__ wdT) {
  __shared__ float wsm[8 * 512];
  __shared__ float us[8];
  __shared__ int cs[8];
  __shared__ __bf16 tile[64][68];
  int bid = blockIdx.x;
  int tid = threadIdx.x;

  if (bid >= 3072) {               // wd transpose: R=INTER, C=HID
    int b = bid - 3072;
    int e = b >> 8;
    int c0 = (b & 7) * 64;
    int r0 = ((b >> 3) & 31) * 64;
    transpose_tile(wd + (size_t)e * INTER * HID, wdT + (size_t)e * INTER * HID,
                   INTER, HID, r0, c0, tile);
    return;
  }
  if (bid >= 1024) {               // wu transpose: R=HID, C=INTER
    int b = bid - 1024;
    int e = b >> 8;
    int c0 = (b & 31) * 64;
    int r0 = ((b >> 5) & 7) * 64;
    transpose_tile(wu + (size_t)e * HID * INTER, wuT + (size_t)e * HID * INTER,
                   HID, INTER, r0, c0, tile);
    return;
  }

  // router
  if (tid < 8) { us[tid] = 0.f; cs[tid] = 0; }
  for (int i = tid; i < 8 * 512; i += 256) {
    int e = i >> 9, h = i & 511;
    wsm[i] = wrt[h * 8 + e];
  }
  __syncthreads();
  int lane = tid & 63;
  int t = bid * 4 + (tid >> 6);
  const float* xt = x + (size_t)t * HID;
  float a[8];
#pragma unroll
  for (int e = 0; e < 8; ++e) a[e] = 0.f;
#pragma unroll
  for (int j = 0; j < 8; ++j) {
    float xv = xt[lane + j * 64];
#pragma unroll
    for (int e = 0; e < 8; ++e) a[e] += xv * wsm[e * 512 + lane + j * 64];
  }
#pragma unroll
  for (int off = 32; off > 0; off >>= 1) {
#pragma unroll
    for (int e = 0; e < 8; ++e) a[e] += __shfl_xor(a[e], off);
  }
  if (lane == 0) {
    float m = a[0];
#pragma unroll
    for (int e = 1; e < 8; ++e) m = fmaxf(m, a[e]);
    float p[8], s = 0.f;
#pragma unroll
    for (int e = 0; e < 8; ++e) { p[e] = expf(a[e] - m); s += p[e]; }
    float inv = 1.f / s;
#pragma unroll
    for (int e = 0; e < 8; ++e) atomicAdd(&us[e], p[e] * inv);
    int i0 = 0; float v0 = a[0];
#pragma unroll
    for (int e = 1; e < 8; ++e) if (a[e] > v0) { v0 = a[e]; i0 = e; }
    int i1 = -1; float v1 = -3.4e38f;
#pragma unroll
    for (int e = 0; e < 8; ++e) if (e != i0 && a[e] > v1) { v1 = a[e]; i1 = e; }
    float e1 = expf(v1 - v0);
    float w0 = 1.f / (1.f + e1);
    float w1 = e1 * w0;
    topi[t * 2] = i0; topi[t * 2 + 1] = i1;
    topw[t * 2] = w0; topw[t * 2 + 1] = w1;
    atomicAdd(&cs[i0], 1); atomicAdd(&cs[i1], 1);
  }
  __syncthreads();
  if (tid < 8) {
    cntpart[bid * 8 + tid] = cs[tid];
    usagepart[bid * 8 + tid] = us[tid];
  }
}

// ---------------- finalize: reduce partials -> cnt/off + loss/usage tail ----------------
__global__ void finalize_kernel(const int* __restrict__ cntpart, const float* __restrict__ usagepart,
                                int* __restrict__ cnt, int* __restrict__ off,
                                float* __restrict__ tail) {
  __shared__ int ci[256];
  __shared__ float uf[256];
  int tid = threadIdx.x;
  int e = tid >> 5, c = tid & 31;
  int s = 0; float u = 0.f;
  for (int b = c; b < 1024; b += 32) {
    s += cntpart[b * 8 + e];
    u += usagepart[b * 8 + e];
  }
  ci[tid] = s; uf[tid] = u;
  __syncthreads();
  for (int st = 16; st > 0; st >>= 1) {
    if (c < st) { ci[tid] += ci[tid + st]; uf[tid] += uf[tid + st]; }
    __syncthreads();
  }
  if (tid == 0) {
    int o = 0;
    float loss = 0.f;
    for (int e2 = 0; e2 < 8; ++e2) {
      int ce = ci[e2 * 32];
      cnt[e2] = ce;
      off[e2] = o;
      o += (ce + 127) & ~127;
      float uu = uf[e2 * 32] * (1.0f / 4096.0f);
      tail[1 + e2] = uu;
      float d = uu - 0.125f;
      loss += d * d;
    }
    tail[0] = loss;
  }
}

// ---------------- slot assignment: ballot-aggregated, 64 total return-atomics ----------------
__global__ void slotassign_kernel(const int* __restrict__ topi, const float* __restrict__ topw,
                                  const int* __restrict__ off, int* __restrict__ cnt2pad,
                                  int* __restrict__ stok, float* __restrict__ sw,
                                  int* __restrict__ slotof) {
  __shared__ int wavehist[16][8];
  __shared__ int blockbase[8];
  int tid = threadIdx.x, lane = tid & 63, wv = tid >> 6;
  int p = blockIdx.x * 1024 + tid;
  int e = topi[p];
  float w = topw[p];
  unsigned long long mymask = 0;
#pragma unroll
  for (int e2 = 0; e2 < 8; ++e2) {
    unsigned long long m = __ballot(e == e2);
    if (lane == 0) wavehist[wv][e2] = __popcll(m);
    if (e2 == e) mymask = m;
  }
  __syncthreads();
  if (tid < 8) {
    int s = 0;
#pragma unroll
    for (int w2 = 0; w2 < 16; ++w2) s += wavehist[w2][tid];
    blockbase[tid] = atomicAdd(&cnt2pad[tid * 16], s);
  }
  __syncthreads();
  int rank = 0;
  for (int w2 = 0; w2 < wv; ++w2) rank += wavehist[w2][e];
  rank += __popcll(mymask & ((1ull << lane) - 1ull));
  int slot = off[e] + blockbase[e] + rank;
  stok[slot] = p >> 1;
  sw[slot] = w;
  slotof[p] = slot;
}

// ---------------- gather: copy token rows (bf16) into expert-grouped Xg, atomic-free --------
__global__ void gather_kernel(const float* __restrict__ x, const int* __restrict__ slotof,
                              __bf16* __restrict__ Xg) {
  int tid = threadIdx.x, lane = tid & 63;
  int p = blockIdx.x * 4 + (tid >> 6);
  int slot = slotof[p];
  int t = p >> 1;
  const float4* xs = (const float4*)(x + (size_t)t * HID);
  float4 v0 = xs[lane * 2], v1 = xs[lane * 2 + 1];
  bf16x8 o;
  o[0] = (__bf16)v0.x; o[1] = (__bf16)v0.y; o[2] = (__bf16)v0.z; o[3] = (__bf16)v0.w;
  o[4] = (__bf16)v1.x; o[5] = (__bf16)v1.y; o[6] = (__bf16)v1.z; o[7] = (__bf16)v1.w;
  *(bf16x8*)(Xg + (size_t)slot * HID + lane * 8) = o;
}

// ---------------- grouped GEMM, 64x64 tile, 4 waves (2x2, 32x32 each), XCD-pinned ----------
// EXACT R13 recipe (best measured: 49 us/GEMM, 0 bank conflicts) with launch_bounds raised
// to (256,8): VGPR=36 and LDS=16KB permit 8 blocks/CU (wave-cap limited); the 6-floor was
// the only untested residency knob in this family.
// up:   r=bid>>3 -> nt = r&31 (fast), mt = r>>5. nk=8 (K=512).     grid 8*24*32 = 6144
// down: r=bid>>3 -> nt = r&7 (fast), mt = r>>3.  nk=32 (K=2048, no split-K). grid 1536
template <int EPI>
__launch_bounds__(256, 8)
__global__ void gemm64(const __bf16* __restrict__ A, const __bf16* __restrict__ Ball,
                       int lda, int ldb, long sB,
                       __bf16* __restrict__ Hout, int ldh,
                       float* __restrict__ Out,
                       const int* __restrict__ stok, const float* __restrict__ sw,
                       const int* __restrict__ offp, const int* __restrict__ cntp) {
  int bid = blockIdx.x;
  int e = bid & 7;               // expert -> XCD pin
  int r = bid >> 3;
  int mt, n0, nk;
  if (EPI == 0) {
    n0 = (r & 31) * 64;          // 32 n-tiles (N=2048), fastest
    mt = r >> 5;                 // 24 m-tile capacity
    nk = 8;                      // K=512
  } else {
    n0 = (r & 7) * 64;           // 8 n-tiles (N=512), fastest
    mt = r >> 3;                 // 24 m-tile capacity
    nk = 32;                     // K=2048, whole (no split-K)
  }
  int cnte = cntp[e];
  if (mt * 64 >= cnte) return;
  int offe = offp[e];
  int m0 = offe + mt * 64;
  const __bf16* B = Ball + (size_t)e * sB;

  __shared__ char smem[16384];    // 8KB A (64x64 bf16) + 8KB B
  char* As = smem;
  char* Bs = smem + 8192;

  int tid = threadIdx.x;
  int lane = tid & 63;
  int wid = tid >> 6;
  int wr = wid >> 1, wc = wid & 1;    // 2x2 waves, 32x32 out each

  f32x4 acc[2][2];
#pragma unroll
  for (int i = 0; i < 2; ++i)
#pragma unroll
    for (int j = 0; j < 2; ++j) acc[i][j] = (f32x4){0.f, 0.f, 0.f, 0.f};

  for (int it = 0; it < nk; ++it) {
    int k0 = it * 64;
#pragma unroll
    for (int q2 = 0; q2 < 2; ++q2) {
      int L = q2 * 4096 + tid * 16;
      int row = L >> 7;
      int kb = L & 127;
      int kbs = kb ^ ((row & 7) << 4);   // inverse-swizzled global source, linear LDS dest
      GLD16((const char*)(A + (size_t)(m0 + row) * lda + k0) + kbs, As + L);
      GLD16((const char*)(B + (size_t)(n0 + row) * (size_t)ldb + k0) + kbs, Bs + L);
    }
    __syncthreads();
#pragma unroll
    for (int ks = 0; ks < 2; ++ks) {
      bf16x8 av[2], bv[2];
      int kb = ks * 64 + ((lane >> 4) << 4);
#pragma unroll
      for (int i = 0; i < 2; ++i) {
        int rowA = wr * 32 + i * 16 + (lane & 15);
        av[i] = *(const bf16x8*)(As + rowA * 128 + (kb ^ ((rowA & 7) << 4)));
        int rowB = wc * 32 + i * 16 + (lane & 15);
        bv[i] = *(const bf16x8*)(Bs + rowB * 128 + (kb ^ ((rowB & 7) << 4)));
      }
#pragma unroll
      for (int i = 0; i < 2; ++i)
#pragma unroll
        for (int j = 0; j < 2; ++j)
          acc[i][j] = __builtin_amdgcn_mfma_f32_16x16x32_bf16(av[i], bv[j], acc[i][j], 0, 0, 0);
    }
    __syncthreads();
  }

  int lim = offe + cnte;
  if (EPI == 0) {
#pragma unroll
    for (int i = 0; i < 2; ++i) {
#pragma unroll
      for (int r2 = 0; r2 < 4; ++r2) {
        int slot = m0 + wr * 32 + i * 16 + ((lane >> 4) << 2) + r2;
        if (slot < lim) {
          __bf16* hp = Hout + (size_t)slot * ldh + n0 + wc * 32 + (lane & 15);
#pragma unroll
          for (int j = 0; j < 2; ++j) {
            float v = acc[i][j][r2];
            float g = 0.5f * v * (1.0f + erff(v * 0.70710678118654752f));
            hp[j * 16] = (__bf16)g;
          }
        }
      }
    }
  } else {
#pragma unroll
    for (int i = 0; i < 2; ++i) {
#pragma unroll
      for (int r2 = 0; r2 < 4; ++r2) {
        int slot = m0 + wr * 32 + i * 16 + ((lane >> 4) << 2) + r2;
        if (slot < lim) {
          int t = stok[slot];
          float w = sw[slot];
          float* op = Out + (size_t)t * HID + n0 + wc * 32 + (lane & 15);
#pragma unroll
          for (int j = 0; j < 2; ++j) atomicAdd(op + j * 16, w * acc[i][j][r2]);
        }
      }
    }
  }
}

extern "C" void kernel_launch(void* const* d_in, const int* in_sizes, int n_in,
                              void* d_out, int out_size, void* d_ws, size_t ws_size,
                              hipStream_t stream) {
  const float* x   = (const float*)d_in[0];
  const float* wrt = (const float*)d_in[1];
  const float* wu  = (const float*)d_in[2];
  const float* wd  = (const float*)d_in[3];
  float* out = (float*)d_out;
  char* ws = (char*)d_ws;

  const size_t XG_OFF   = 0;
  const size_t H_OFF    = XG_OFF  + (size_t)9216 * 512 * 2;
  const size_t WUT_OFF  = H_OFF   + (size_t)9216 * 2048 * 2;
  const size_t WDT_OFF  = WUT_OFF + (size_t)8 * 512 * 2048 * 2;
  const size_t TOK_OFF  = WDT_OFF + (size_t)8 * 512 * 2048 * 2;
  const size_t SW_OFF   = TOK_OFF  + (size_t)9216 * 4;
  const size_t TOPI_OFF = SW_OFF   + (size_t)9216 * 4;
  const size_t TOPW_OFF = TOPI_OFF + (size_t)8192 * 4;
  const size_t SLOT_OFF = TOPW_OFF + (size_t)8192 * 4;
  const size_t CPART_OFF = SLOT_OFF + (size_t)8192 * 4;
  const size_t UPART_OFF = CPART_OFF + (size_t)8192 * 4;
  const size_t CTRL_OFF  = UPART_OFF + (size_t)8192 * 4;
  // CTRL: cnt[8] @0, off[8] @64, cnt2pad[8*16] @128  (memset 1KB)

  __bf16* Xg   = (__bf16*)(ws + XG_OFF);
  __bf16* H    = (__bf16*)(ws + H_OFF);
  __bf16* wuT  = (__bf16*)(ws + WUT_OFF);
  __bf16* wdT  = (__bf16*)(ws + WDT_OFF);
  int*    stok = (int*)(ws + TOK_OFF);
  float*  sw   = (float*)(ws + SW_OFF);
  int*    topi = (int*)(ws + TOPI_OFF);
  float*  topw = (float*)(ws + TOPW_OFF);
  int*    slotof = (int*)(ws + SLOT_OFF);
  int*    cntpart = (int*)(ws + CPART_OFF);
  float*  usagepart = (float*)(ws + UPART_OFF);
  int*    cnt  = (int*)(ws + CTRL_OFF);
  int*    off  = (int*)(ws + CTRL_OFF + 64);
  int*    cnt2pad = (int*)(ws + CTRL_OFF + 128);

  hipMemsetAsync(ws + CTRL_OFF, 0, 1024, stream);
  hipMemsetAsync(d_out, 0, (size_t)T_TOKENS * HID * 4, stream);

  // fused: router (1024) + wu transpose (2048) + wd transpose (2048)
  prep_kernel<<<5120, 256, 0, stream>>>(x, wrt, topi, topw, cntpart, usagepart,
                                        wu, wuT, wd, wdT);
  finalize_kernel<<<1, 256, 0, stream>>>(cntpart, usagepart, cnt, off,
                                         out + (size_t)T_TOKENS * HID);
  slotassign_kernel<<<8, 1024, 0, stream>>>(topi, topw, off, cnt2pad, stok, sw, slotof);
  gather_kernel<<<2048, 256, 0, stream>>>(x, slotof, Xg);

  // up: h = gelu(Xg @ wuT^T); grid = 8e * (24mt * 32nt) = 6144, e = bid&7 (XCD-pinned)
  gemm64<0><<<6144, 256, 0, stream>>>(
      Xg, wuT, HID, HID, (long)INTER * HID, H, INTER,
      nullptr, nullptr, nullptr, off, cnt);
  // down: out += w*(h @ wdT^T); grid = 8e * (8nt * 24mt) = 1536, full K (no split)
  gemm64<1><<<1536, 256, 0, stream>>>(
      H, wdT, INTER, INTER, (long)INTER * HID, nullptr, 0,
      out, stok, sw, off, cnt);
}